// Round 3
// baseline (306.634 us; speedup 1.0000x reference)
//
#include <hip/hip_runtime.h>

// TTN Conv: out[n,p,o,site] = sum_{c,i,j,k,l} a_i b_j c_k d_l * W[c,p,site,ijkl,o] + bias
// Per site: GEMM D[n=128][po=48] = sum_k A[n][k=768] * W[k][po], bf16 MFMA 16x16x32.
//
// x:       (128, 3, 4, 32, 32) fp32
// tensors: (3, 8, 31, 31, 256, 6) fp32  -> per (c,p,site): [m=256][o=6] contiguous
// bias:    (8, 31, 31, 6) fp32
// out:     (128, 8, 6, 31, 31) fp32 = out[f*961 + site], f = n*48 + p*6 + o
//
// R5. R4 passed but conv regressed 85->140us: WRITE_SIZE 23->161 MB revealed
// ~48 B/thread/chunk of scratch = the `float vv[12]` sW-staging array (SROA
// failed on the ternary-float4-initialized local; it lived in memory, 12
// stores + 12 loads per chunk). Fix: stage sW with SIX EXPLICIT component
// pairs -- no indexable local anywhere in the staging path (rule #20 family).
// Everything else identical to R4:
//  * A-fragments built IN REGISTERS: lane (row,quad) computes its own 8 A values
//      A[n][ks*32+quad*8+e] = a[mb] * b[ks*2+(quad>>1)] * cd[(quad&1)*8+e]
//    from per-lane x scalars for its 2 n-rows. No sA, one barrier per chunk.
//  * sW double-buffered (2 x 6.9 KB); ONE fused "s_waitcnt lgkmcnt(0); s_barrier"
//    asm volatile w/ memory clobber per chunk (compiler fence both directions,
//    vmcnt untouched -> global W prefetch rides across barriers, T3/T4).
//    Safety: chunk ch stages buf=ch&1; compute(ch) readers of that buf are
//    lgkm-drained at barrier(ch+1), which precedes stage(ch+2) for every wave.
//  * W prefetch 2 chunks deep in 2 register sets (gap ~2 chunk periods).
//  * v_cvt_pk_bf16_f32 packs pairs along k for BOTH A and W operands, so the
//    lo/hi convention cancels in the dot product.
// Phase 2: tiled transpose ws(961 x 6144) -> out(6144 x 961) + bias (unchanged).

typedef __attribute__((ext_vector_type(8))) short short8;
typedef __attribute__((ext_vector_type(4))) float floatx4;

#define WS_ELEMS (961u * 6144u)
#define SW_STR 72           // 64+8 shorts: granule shift -> 2-way max on b128 reads (free)
#define C_STRIDE 11808768   // 8*961*1536 floats between c panels

static __device__ __forceinline__ unsigned cvt_pk_bf16(float lo, float hi) {
  unsigned r;
  asm("v_cvt_pk_bf16_f32 %0, %1, %2" : "=v"(r) : "v"(lo), "v"(hi));
  return r;
}

// lgkm drain + workgroup barrier as ONE volatile asm with memory clobber:
// compiler may not move any memory op across it; vmcnt left untouched so
// global prefetch loads stay in flight.
static __device__ __forceinline__ void barrier_lgkm() {
  asm volatile("s_waitcnt lgkmcnt(0)\n\ts_barrier" ::: "memory");
  __builtin_amdgcn_sched_barrier(0);
}

template <bool TO_WS>
__global__ __launch_bounds__(256, 4)
void ttn_conv_mfma(const float* __restrict__ x,
                   const float* __restrict__ tensors,
                   const float* __restrict__ bias,
                   float* __restrict__ dst) {
  __shared__ __align__(16) unsigned short sW[2][48 * SW_STR];  // 2 x 6912 B

  const int site = blockIdx.x;
  const int xx = site / 31, yy = site - xx * 31;
  const int t = threadIdx.x;
  const int lane = t & 63, wave = t >> 6;
  const int row = lane & 15, quad = lane >> 4;
  const int p_st = t >> 5;        // sW staging: p (0..7)
  const int q_st = t & 31;        // sW staging: m-pair index (m = 2q, 2q+1)
  const int k0 = (quad & 1) * 2;  // this lane's c_k index base (kl = (quad&1)*8 + e)

  floatx4 acc[2][3];
#pragma unroll
  for (int i0 = 0; i0 < 2; ++i0)
#pragma unroll
    for (int j0 = 0; j0 < 3; ++j0)
      acc[i0][j0] = (floatx4){0.f, 0.f, 0.f, 0.f};

  // per-lane x factors for the two n-rows this lane feeds (mt = 0,1)
  float a_[2][4];        // a_i (constant-indexed only: mb is unroll-constant)
  float bsel[2][2];      // b_{ks*2 + (quad>>1)} pre-selected per K-step
  float cd_[2][8];       // c_{k0 + (e>>2)} * d_{e&3}

  const float* wbase = tensors + ((size_t)(p_st * 961 + site)) * 1536 + 12 * q_st;

  // W prefetch register sets: set A holds even chunks, set B odd chunks.
  float4 wa0, wa1, wa2, wb0, wb1, wb2;
  wa0 = *(const float4*)(wbase + 0);      // chunk 0 (c=0, mb=0)
  wa1 = *(const float4*)(wbase + 4);
  wa2 = *(const float4*)(wbase + 8);
  wb0 = *(const float4*)(wbase + 384);    // chunk 1 (c=0, mb=1)
  wb1 = *(const float4*)(wbase + 388);
  wb2 = *(const float4*)(wbase + 392);

#pragma unroll
  for (int ch = 0; ch < 12; ++ch) {
    const int mb = ch & 3;

    if (mb == 0) {
      // x factors for c = ch>>2, both n-rows. Scalar loads (4B-aligned only).
      const int c = ch >> 2;
#pragma unroll
      for (int nn = 0; nn < 2; ++nn) {
        const int n = wave * 32 + nn * 16 + row;
        const float* xp = x + ((size_t)n * 3 + c) * 4096 + xx * 32 + yy;
        float bq[4], dq[4];
#pragma unroll
        for (int i = 0; i < 4; ++i) {
          const float* r0 = xp + i * 1024;
          a_[nn][i] = r0[0];    // a_i = x[n,c,i,xx,  yy  ]
          bq[i]     = r0[32];   // b_i = x[n,c,i,xx+1,yy  ]
          dq[i]     = r0[33];   // d_i = x[n,c,i,xx+1,yy+1]
        }
        // explicit select (v_cndmask), NOT runtime array index (rule #20)
        bsel[nn][0] = (quad & 2) ? bq[1] : bq[0];
        bsel[nn][1] = (quad & 2) ? bq[3] : bq[2];
        const float cq0 = xp[k0 * 1024 + 1];        // c_{k0}   = x[n,c,k0,  xx,yy+1]
        const float cq1 = xp[(k0 + 1) * 1024 + 1];  // c_{k0+1}
#pragma unroll
        for (int l = 0; l < 4; ++l) {
          cd_[nn][l]     = cq0 * dq[l];
          cd_[nn][4 + l] = cq1 * dq[l];
        }
      }
    }

    // ---- stage sW[ch&1][po][m_local] from this chunk's register set ----
    // Explicit component pairs (m=2q -> lo, m=2q+1 -> hi); NO local array.
    // W[2q][o] = src[12q + o], W[2q+1][o] = src[12q + 6 + o]:
    //   o: 0->(w0.x,w1.z) 1->(w0.y,w1.w) 2->(w0.z,w2.x)
    //      3->(w0.w,w2.y) 4->(w1.x,w2.z) 5->(w1.y,w2.w)
    {
      const float4 w0 = (ch & 1) ? wb0 : wa0;
      const float4 w1 = (ch & 1) ? wb1 : wa1;
      const float4 w2 = (ch & 1) ? wb2 : wa2;
      unsigned short* dW = &sW[ch & 1][p_st * 6 * SW_STR + 2 * q_st];
      *(unsigned*)&dW[0 * SW_STR] = cvt_pk_bf16(w0.x, w1.z);
      *(unsigned*)&dW[1 * SW_STR] = cvt_pk_bf16(w0.y, w1.w);
      *(unsigned*)&dW[2 * SW_STR] = cvt_pk_bf16(w0.z, w2.x);
      *(unsigned*)&dW[3 * SW_STR] = cvt_pk_bf16(w0.w, w2.y);
      *(unsigned*)&dW[4 * SW_STR] = cvt_pk_bf16(w1.x, w2.z);
      *(unsigned*)&dW[5 * SW_STR] = cvt_pk_bf16(w1.y, w2.w);
    }

    // ---- prefetch chunk ch+2 into the set just consumed (stays in flight
    //      across the fused barrier below -- vmcnt untouched) ----
    if (ch + 2 < 12) {
      const float* src =
          wbase + (size_t)((ch + 2) >> 2) * C_STRIDE + ((ch + 2) & 3) * 384;
      const float4 n0 = *(const float4*)src;
      const float4 n1 = *(const float4*)(src + 4);
      const float4 n2 = *(const float4*)(src + 8);
      if (ch & 1) { wb0 = n0; wb1 = n1; wb2 = n2; }
      else        { wa0 = n0; wa1 = n1; wa2 = n2; }
    }

    // One fused barrier per chunk: LDS writes drained + barrier, compiler
    // memory fence both directions; global loads left in flight.
    barrier_lgkm();

    // ---- compute: 2 K-steps of 32, wave tile 2(M) x 3(N), A built in regs ----
#pragma unroll
    for (int ks = 0; ks < 2; ++ks) {
      short8 af[2], bf[3];
#pragma unroll
      for (int mt = 0; mt < 2; ++mt) {
        const float ab = a_[mt][mb] * bsel[mt][ks];
        union { unsigned u[4]; short8 s; } pk;
        pk.u[0] = cvt_pk_bf16(ab * cd_[mt][0], ab * cd_[mt][1]);
        pk.u[1] = cvt_pk_bf16(ab * cd_[mt][2], ab * cd_[mt][3]);
        pk.u[2] = cvt_pk_bf16(ab * cd_[mt][4], ab * cd_[mt][5]);
        pk.u[3] = cvt_pk_bf16(ab * cd_[mt][6], ab * cd_[mt][7]);
        af[mt] = pk.s;
      }
      const int kof = ks * 32 + quad * 8;
#pragma unroll
      for (int nt = 0; nt < 3; ++nt)
        bf[nt] = *(const short8*)&sW[ch & 1][(nt * 16 + row) * SW_STR + kof];
#pragma unroll
      for (int mt = 0; mt < 2; ++mt)
#pragma unroll
        for (int nt = 0; nt < 3; ++nt)
          acc[mt][nt] = __builtin_amdgcn_mfma_f32_16x16x32_bf16(
              af[mt], bf[nt], acc[mt][nt], 0, 0, 0);
    }
    // No trailing barrier: next chunk stages the OTHER buffer; the chunk-(ch+1)
    // barrier orders this chunk's readers vs chunk-(ch+2)'s writers.
  }

  // ---- epilogue: D row = quad*4+r (n-local), col = lane&15 (po-local) ----
  if (TO_WS) {
#pragma unroll
    for (int mt = 0; mt < 2; ++mt)
#pragma unroll
      for (int r = 0; r < 4; ++r) {
        const int n = wave * 32 + mt * 16 + quad * 4 + r;
#pragma unroll
        for (int nt = 0; nt < 3; ++nt) {
          const int po = nt * 16 + row;
          dst[(size_t)site * 6144 + n * 48 + po] = acc[mt][nt][r];
        }
      }
  } else {
#pragma unroll
    for (int mt = 0; mt < 2; ++mt)
#pragma unroll
      for (int r = 0; r < 4; ++r) {
        const int n = wave * 32 + mt * 16 + quad * 4 + r;
#pragma unroll
        for (int nt = 0; nt < 3; ++nt) {
          const int po = nt * 16 + row;
          const int p = po / 6, o = po - p * 6;
          dst[(size_t)(n * 48 + po) * 961 + site] =
              acc[mt][nt][r] + bias[(p * 961 + site) * 6 + o];
        }
      }
  }
}

// out[f*961 + site] = ws[site*6144 + f] + bias[(p*961+site)*6 + o],  f = n*48+p*6+o
__global__ __launch_bounds__(256, 8)
void ttn_transpose_bias(const float* __restrict__ ws,
                        const float* __restrict__ bias,
                        float* __restrict__ out) {
  __shared__ float tile[32][33];
  const int f0 = blockIdx.x * 32;
  const int s0 = blockIdx.y * 32;
  const int tx = threadIdx.x;       // 0..31
  const int ty = threadIdx.y;       // 0..7

#pragma unroll
  for (int rr = 0; rr < 4; ++rr) {
    const int srow = ty + rr * 8;
    const int site = s0 + srow;
    if (site < 961)
      tile[srow][tx] = ws[(size_t)site * 6144 + f0 + tx];
  }
  __syncthreads();

#pragma unroll
  for (int rr = 0; rr < 4; ++rr) {
    const int fy = ty + rr * 8;
    const int f = f0 + fy;
    const int site = s0 + tx;
    if (site < 961) {
      const int po = f % 48;
      const int p = po / 6, o = po - p * 6;
      out[(size_t)f * 961 + site] = tile[tx][fy] + bias[(p * 961 + site) * 6 + o];
    }
  }
}

extern "C" void kernel_launch(void* const* d_in, const int* in_sizes, int n_in,
                              void* d_out, int out_size, void* d_ws, size_t ws_size,
                              hipStream_t stream) {
  const float* x       = (const float*)d_in[0];
  const float* tensors = (const float*)d_in[1];
  const float* bias    = (const float*)d_in[2];
  float* out           = (float*)d_out;

  const size_t need = (size_t)WS_ELEMS * sizeof(float);
  if (d_ws != nullptr && ws_size >= need) {
    float* ws = (float*)d_ws;
    hipLaunchKernelGGL((ttn_conv_mfma<true>), dim3(961), dim3(256), 0, stream,
                       x, tensors, bias, ws);
    hipLaunchKernelGGL(ttn_transpose_bias, dim3(192, 31), dim3(32, 8), 0, stream,
                       ws, bias, out);
  } else {
    hipLaunchKernelGGL((ttn_conv_mfma<false>), dim3(961), dim3(256), 0, stream,
                       x, tensors, bias, out);
  }
}

// Round 4
// 304.226 us; speedup vs baseline: 1.0079x; 1.0079x over previous
//
#include <hip/hip_runtime.h>

// TTN Conv: out[n,p,o,site] = sum_{c,i,j,k,l} a_i b_j c_k d_l * W[c,p,site,ijkl,o] + bias
// Per site: GEMM D[n=128][po=48] = sum_k A[n][k=768] * W[k][po], bf16 MFMA 16x16x32.
//
// x:       (128, 3, 4, 32, 32) fp32
// tensors: (3, 8, 31, 31, 256, 6) fp32  -> per (c,p,site): [m=256][o=6] contiguous
// bias:    (8, 31, 31, 6) fp32
// out:     (128, 8, 6, 31, 31) fp32 = out[f*961 + site], f = n*48 + p*6 + o
//
// R6. R4/R5 both showed WRITE_SIZE ~165-172 MB (real output: 23.6 MB) -- scratch.
// Differential: removing vv[12] (R5) changed nothing => the scratch was the
// union{u[4]; short8} fragment-assembly in the MFMA loop (union punning defeats
// SROA; 4x(16B st + 16B ld) per thread-chunk ~ 189 MB each way). Fix: build the
// fragment as an ext-vector literal + __builtin_bit_cast -> pure SSA, no union,
// no addressable local. Everything else frozen from R5:
//  * A-fragments built IN REGISTERS: lane (row,quad) computes its own 8 A values
//      A[n][ks*32+quad*8+e] = a[mb] * b[ks*2+(quad>>1)] * cd[(quad&1)*8+e]
//    from per-lane x scalars for its 2 n-rows. No sA, one barrier per chunk.
//  * sW double-buffered (2 x 6.9 KB); ONE fused "s_waitcnt lgkmcnt(0); s_barrier"
//    asm volatile w/ memory clobber per chunk (compiler fence both directions,
//    vmcnt untouched -> global W prefetch rides across barriers, T3/T4).
//    Safety: chunk ch stages buf=ch&1; compute(ch) readers of that buf are
//    lgkm-drained at barrier(ch+1), which precedes stage(ch+2) for every wave.
//  * W prefetch 2 chunks deep in 2 register sets (gap ~2 chunk periods).
//  * v_cvt_pk_bf16_f32 packs pairs along k for BOTH A and W operands, so the
//    lo/hi convention cancels in the dot product.
// Phase 2: tiled transpose ws(961 x 6144) -> out(6144 x 961) + bias (unchanged).

typedef __attribute__((ext_vector_type(8))) short short8;
typedef __attribute__((ext_vector_type(4))) float floatx4;
typedef __attribute__((ext_vector_type(4))) unsigned uintx4;

#define WS_ELEMS (961u * 6144u)
#define SW_STR 72           // 64+8 shorts: granule shift -> 2-way max on b128 reads (free)
#define C_STRIDE 11808768   // 8*961*1536 floats between c panels

static __device__ __forceinline__ unsigned cvt_pk_bf16(float lo, float hi) {
  unsigned r;
  asm("v_cvt_pk_bf16_f32 %0, %1, %2" : "=v"(r) : "v"(lo), "v"(hi));
  return r;
}

// lgkm drain + workgroup barrier as ONE volatile asm with memory clobber:
// compiler may not move any memory op across it; vmcnt left untouched so
// global prefetch loads stay in flight.
static __device__ __forceinline__ void barrier_lgkm() {
  asm volatile("s_waitcnt lgkmcnt(0)\n\ts_barrier" ::: "memory");
  __builtin_amdgcn_sched_barrier(0);
}

template <bool TO_WS>
__global__ __launch_bounds__(256, 4)
void ttn_conv_mfma(const float* __restrict__ x,
                   const float* __restrict__ tensors,
                   const float* __restrict__ bias,
                   float* __restrict__ dst) {
  __shared__ __align__(16) unsigned short sW[2][48 * SW_STR];  // 2 x 6912 B

  const int site = blockIdx.x;
  const int xx = site / 31, yy = site - xx * 31;
  const int t = threadIdx.x;
  const int lane = t & 63, wave = t >> 6;
  const int row = lane & 15, quad = lane >> 4;
  const int p_st = t >> 5;        // sW staging: p (0..7)
  const int q_st = t & 31;        // sW staging: m-pair index (m = 2q, 2q+1)
  const int k0 = (quad & 1) * 2;  // this lane's c_k index base (kl = (quad&1)*8 + e)

  floatx4 acc[2][3];
#pragma unroll
  for (int i0 = 0; i0 < 2; ++i0)
#pragma unroll
    for (int j0 = 0; j0 < 3; ++j0)
      acc[i0][j0] = (floatx4){0.f, 0.f, 0.f, 0.f};

  // per-lane x factors for the two n-rows this lane feeds (mt = 0,1)
  float a_[2][4];        // a_i (constant-indexed only: mb is unroll-constant)
  float bsel[2][2];      // b_{ks*2 + (quad>>1)} pre-selected per K-step
  float cd_[2][8];       // c_{k0 + (e>>2)} * d_{e&3}

  const float* wbase = tensors + ((size_t)(p_st * 961 + site)) * 1536 + 12 * q_st;

  // W prefetch register sets: set A holds even chunks, set B odd chunks.
  float4 wa0, wa1, wa2, wb0, wb1, wb2;
  wa0 = *(const float4*)(wbase + 0);      // chunk 0 (c=0, mb=0)
  wa1 = *(const float4*)(wbase + 4);
  wa2 = *(const float4*)(wbase + 8);
  wb0 = *(const float4*)(wbase + 384);    // chunk 1 (c=0, mb=1)
  wb1 = *(const float4*)(wbase + 388);
  wb2 = *(const float4*)(wbase + 392);

#pragma unroll
  for (int ch = 0; ch < 12; ++ch) {
    const int mb = ch & 3;

    if (mb == 0) {
      // x factors for c = ch>>2, both n-rows. Scalar loads (4B-aligned only).
      const int c = ch >> 2;
#pragma unroll
      for (int nn = 0; nn < 2; ++nn) {
        const int n = wave * 32 + nn * 16 + row;
        const float* xp = x + ((size_t)n * 3 + c) * 4096 + xx * 32 + yy;
        float bq[4], dq[4];
#pragma unroll
        for (int i = 0; i < 4; ++i) {
          const float* r0 = xp + i * 1024;
          a_[nn][i] = r0[0];    // a_i = x[n,c,i,xx,  yy  ]
          bq[i]     = r0[32];   // b_i = x[n,c,i,xx+1,yy  ]
          dq[i]     = r0[33];   // d_i = x[n,c,i,xx+1,yy+1]
        }
        // explicit select (v_cndmask), NOT runtime array index (rule #20)
        bsel[nn][0] = (quad & 2) ? bq[1] : bq[0];
        bsel[nn][1] = (quad & 2) ? bq[3] : bq[2];
        const float cq0 = xp[k0 * 1024 + 1];        // c_{k0}   = x[n,c,k0,  xx,yy+1]
        const float cq1 = xp[(k0 + 1) * 1024 + 1];  // c_{k0+1}
#pragma unroll
        for (int l = 0; l < 4; ++l) {
          cd_[nn][l]     = cq0 * dq[l];
          cd_[nn][4 + l] = cq1 * dq[l];
        }
      }
    }

    // ---- stage sW[ch&1][po][m_local] from this chunk's register set ----
    // Explicit component pairs (m=2q -> lo, m=2q+1 -> hi); NO local array.
    // W[2q][o] = src[12q + o], W[2q+1][o] = src[12q + 6 + o]:
    //   o: 0->(w0.x,w1.z) 1->(w0.y,w1.w) 2->(w0.z,w2.x)
    //      3->(w0.w,w2.y) 4->(w1.x,w2.z) 5->(w1.y,w2.w)
    {
      const float4 w0 = (ch & 1) ? wb0 : wa0;
      const float4 w1 = (ch & 1) ? wb1 : wa1;
      const float4 w2 = (ch & 1) ? wb2 : wa2;
      unsigned short* dW = &sW[ch & 1][p_st * 6 * SW_STR + 2 * q_st];
      *(unsigned*)&dW[0 * SW_STR] = cvt_pk_bf16(w0.x, w1.z);
      *(unsigned*)&dW[1 * SW_STR] = cvt_pk_bf16(w0.y, w1.w);
      *(unsigned*)&dW[2 * SW_STR] = cvt_pk_bf16(w0.z, w2.x);
      *(unsigned*)&dW[3 * SW_STR] = cvt_pk_bf16(w0.w, w2.y);
      *(unsigned*)&dW[4 * SW_STR] = cvt_pk_bf16(w1.x, w2.z);
      *(unsigned*)&dW[5 * SW_STR] = cvt_pk_bf16(w1.y, w2.w);
    }

    // ---- prefetch chunk ch+2 into the set just consumed (stays in flight
    //      across the fused barrier below -- vmcnt untouched) ----
    if (ch + 2 < 12) {
      const float* src =
          wbase + (size_t)((ch + 2) >> 2) * C_STRIDE + ((ch + 2) & 3) * 384;
      const float4 n0 = *(const float4*)src;
      const float4 n1 = *(const float4*)(src + 4);
      const float4 n2 = *(const float4*)(src + 8);
      if (ch & 1) { wb0 = n0; wb1 = n1; wb2 = n2; }
      else        { wa0 = n0; wa1 = n1; wa2 = n2; }
    }

    // One fused barrier per chunk: LDS writes drained + barrier, compiler
    // memory fence both directions; global loads left in flight.
    barrier_lgkm();

    // ---- compute: 2 K-steps of 32, wave tile 2(M) x 3(N), A built in regs ----
#pragma unroll
    for (int ks = 0; ks < 2; ++ks) {
      short8 af[2], bf[3];
#pragma unroll
      for (int mt = 0; mt < 2; ++mt) {
        const float ab = a_[mt][mb] * bsel[mt][ks];
        // ext-vector literal + bit_cast: pure SSA (insertelement), no union,
        // no addressable local -> no scratch (R4/R5 lesson).
        const uintx4 u = {cvt_pk_bf16(ab * cd_[mt][0], ab * cd_[mt][1]),
                          cvt_pk_bf16(ab * cd_[mt][2], ab * cd_[mt][3]),
                          cvt_pk_bf16(ab * cd_[mt][4], ab * cd_[mt][5]),
                          cvt_pk_bf16(ab * cd_[mt][6], ab * cd_[mt][7])};
        af[mt] = __builtin_bit_cast(short8, u);
      }
      const int kof = ks * 32 + quad * 8;
#pragma unroll
      for (int nt = 0; nt < 3; ++nt)
        bf[nt] = *(const short8*)&sW[ch & 1][(nt * 16 + row) * SW_STR + kof];
#pragma unroll
      for (int mt = 0; mt < 2; ++mt)
#pragma unroll
        for (int nt = 0; nt < 3; ++nt)
          acc[mt][nt] = __builtin_amdgcn_mfma_f32_16x16x32_bf16(
              af[mt], bf[nt], acc[mt][nt], 0, 0, 0);
    }
    // No trailing barrier: next chunk stages the OTHER buffer; the chunk-(ch+1)
    // barrier orders this chunk's readers vs chunk-(ch+2)'s writers.
  }

  // ---- epilogue: D row = quad*4+r (n-local), col = lane&15 (po-local) ----
  if (TO_WS) {
#pragma unroll
    for (int mt = 0; mt < 2; ++mt)
#pragma unroll
      for (int r = 0; r < 4; ++r) {
        const int n = wave * 32 + mt * 16 + quad * 4 + r;
#pragma unroll
        for (int nt = 0; nt < 3; ++nt) {
          const int po = nt * 16 + row;
          dst[(size_t)site * 6144 + n * 48 + po] = acc[mt][nt][r];
        }
      }
  } else {
#pragma unroll
    for (int mt = 0; mt < 2; ++mt)
#pragma unroll
      for (int r = 0; r < 4; ++r) {
        const int n = wave * 32 + mt * 16 + quad * 4 + r;
#pragma unroll
        for (int nt = 0; nt < 3; ++nt) {
          const int po = nt * 16 + row;
          const int p = po / 6, o = po - p * 6;
          dst[(size_t)(n * 48 + po) * 961 + site] =
              acc[mt][nt][r] + bias[(p * 961 + site) * 6 + o];
        }
      }
  }
}

// out[f*961 + site] = ws[site*6144 + f] + bias[(p*961+site)*6 + o],  f = n*48+p*6+o
__global__ __launch_bounds__(256, 8)
void ttn_transpose_bias(const float* __restrict__ ws,
                        const float* __restrict__ bias,
                        float* __restrict__ out) {
  __shared__ float tile[32][33];
  const int f0 = blockIdx.x * 32;
  const int s0 = blockIdx.y * 32;
  const int tx = threadIdx.x;       // 0..31
  const int ty = threadIdx.y;       // 0..7

#pragma unroll
  for (int rr = 0; rr < 4; ++rr) {
    const int srow = ty + rr * 8;
    const int site = s0 + srow;
    if (site < 961)
      tile[srow][tx] = ws[(size_t)site * 6144 + f0 + tx];
  }
  __syncthreads();

#pragma unroll
  for (int rr = 0; rr < 4; ++rr) {
    const int fy = ty + rr * 8;
    const int f = f0 + fy;
    const int site = s0 + tx;
    if (site < 961) {
      const int po = f % 48;
      const int p = po / 6, o = po - p * 6;
      out[(size_t)f * 961 + site] = tile[tx][fy] + bias[(p * 961 + site) * 6 + o];
    }
  }
}

extern "C" void kernel_launch(void* const* d_in, const int* in_sizes, int n_in,
                              void* d_out, int out_size, void* d_ws, size_t ws_size,
                              hipStream_t stream) {
  const float* x       = (const float*)d_in[0];
  const float* tensors = (const float*)d_in[1];
  const float* bias    = (const float*)d_in[2];
  float* out           = (float*)d_out;

  const size_t need = (size_t)WS_ELEMS * sizeof(float);
  if (d_ws != nullptr && ws_size >= need) {
    float* ws = (float*)d_ws;
    hipLaunchKernelGGL((ttn_conv_mfma<true>), dim3(961), dim3(256), 0, stream,
                       x, tensors, bias, ws);
    hipLaunchKernelGGL(ttn_transpose_bias, dim3(192, 31), dim3(32, 8), 0, stream,
                       ws, bias, out);
  } else {
    hipLaunchKernelGGL((ttn_conv_mfma<false>), dim3(961), dim3(256), 0, stream,
                       x, tensors, bias, out);
  }
}

// Round 5
// 243.093 us; speedup vs baseline: 1.2614x; 1.2515x over previous
//
#include <hip/hip_runtime.h>

// TTN Conv: out[n,p,o,site] = sum_{c,i,j,k,l} a_i b_j c_k d_l * W[c,p,site,ijkl,o] + bias
// Per site: GEMM D[n=128][po=48] = sum_k A[n][k=768] * W[k][po], bf16 MFMA 16x16x32.
//
// x:       (128, 3, 4, 32, 32) fp32
// tensors: (3, 8, 31, 31, 256, 6) fp32  -> per (c,p,site): [m=256][o=6] contiguous
// bias:    (8, 31, 31, 6) fp32
// out:     (128, 8, 6, 31, 31) fp32 = out[f*961 + site], f = n*48 + p*6 + o
//
// R7 = R0 baseline (proven clean codegen: WRITE 23 MB, VGPR 60, 85us) with ONE
// surgical change: both __syncthreads() -> fused "s_waitcnt lgkmcnt(0); s_barrier"
// (single asm volatile w/ memory clobber, + sched_barrier(0), the R2-proven
// race-free form). Rationale: sA and sW are staged FROM REGISTERS, so barrier
// correctness needs only ds_write->ds_read visibility (lgkm); __syncthreads'
// vmcnt(0) drain killed the 1-chunk W prefetch 24x per block. Global loads are
// consumed via register deps (compiler inserts counted vmcnt waits).
// NOTE: R3-R6 (A-in-registers restructure) all hit a structural ~148 MB scratch
// inflation (WRITE 172 MB, conv 140us) that survived 3 local-removal fixes --
// abandoned; this round returns to the known-clean structure.
//
// Phase 1 (1 block/site, 256 thr = 4 waves): K in 12 chunks of 64 (c x mb).
//   sA[128][64] bf16 (stride 72): A[n][ij4*16+kl] = a_mb*b_j * c_k*d_l, from regs.
//   sW[48][64] bf16 (stride 72):  sW[p*6+o][m] transposed from global, b32 writes.
//   W prefetched one chunk ahead in regs. Wave w: n in [w*32,w*32+32), 2x3 MFMA.
//   Epilogue -> ws[site][n*48+po]: each store instr covers 4 full 64B lines.
// Phase 2: tiled transpose ws(961 x 6144) -> out(6144 x 961) + bias.
//
// Stride 72 = 64+8: row shift of one 16B granule -> even granule spread on all
// b128 LDS ops (2-way max, free per m136).

typedef __attribute__((ext_vector_type(8))) short short8;
typedef __attribute__((ext_vector_type(4))) float floatx4;
typedef __attribute__((ext_vector_type(4))) unsigned int uintx4;

#define WS_ELEMS (961u * 6144u)
#define SA_STR 72
#define SW_STR 72

static __device__ __forceinline__ unsigned short f2bf(float f) {
  union { float f; unsigned u; } v; v.f = f;
  unsigned r = v.u + 0x7FFFu + ((v.u >> 16) & 1u);   // RNE to bf16
  return (unsigned short)(r >> 16);
}

// lgkm drain + workgroup barrier as ONE volatile asm with memory clobber:
// compiler may not move any memory op across it; vmcnt left untouched so
// global prefetch loads stay in flight across the barrier (T4).
static __device__ __forceinline__ void barrier_lgkm() {
  asm volatile("s_waitcnt lgkmcnt(0)\n\ts_barrier" ::: "memory");
  __builtin_amdgcn_sched_barrier(0);
}

template <bool TO_WS>
__global__ __launch_bounds__(256, 4)
void ttn_conv_mfma(const float* __restrict__ x,
                   const float* __restrict__ tensors,
                   const float* __restrict__ bias,
                   float* __restrict__ dst) {
  __shared__ __align__(16) unsigned short sA[128 * SA_STR];  // 18432 B
  __shared__ __align__(16) unsigned short sW[48 * SW_STR];   //  6912 B

  const int site = blockIdx.x;
  const int xx = site / 31, yy = site - xx * 31;
  const int t = threadIdx.x;
  const int lane = t & 63, wave = t >> 6;
  const int row = lane & 15, quad = lane >> 4;

  const int n_st = t & 127;   // sA staging: this thread's n
  const int h = t >> 7;       // sA staging: ij4 in {2h, 2h+1}  (j = 2h+e, i = mb)
  const int p_st = t >> 5;    // sW staging: p (0..7)
  const int q_st = t & 31;    // sW staging: m-pair index (m = 2q, 2q+1)

  floatx4 acc[2][3];
#pragma unroll
  for (int i0 = 0; i0 < 2; ++i0)
#pragma unroll
    for (int j0 = 0; j0 < 3; ++j0)
      acc[i0][j0] = (floatx4){0.f, 0.f, 0.f, 0.f};

  float areg[4], b0 = 0.f, b1 = 0.f, cdreg[16];
  float4 wv0, wv1, wv2;

  // prefetch W chunk 0 (c=0, mb=0)
  {
    const float* src = tensors + ((size_t)(p_st * 961 + site)) * 1536 + 12 * q_st;
    wv0 = *(const float4*)src;
    wv1 = *(const float4*)(src + 4);
    wv2 = *(const float4*)(src + 8);
  }

#pragma unroll
  for (int ch = 0; ch < 12; ++ch) {
    const int mb = ch & 3;
    if ((ch & 3) == 0) {
      const int c = ch >> 2;
      // load x factors for this c (scalar loads: 4B-aligned only)
      const float* xp = x + ((size_t)n_st * 3 + c) * 4096 + xx * 32 + yy;
      float bq[4], cq[4], dq[4];
#pragma unroll
      for (int i = 0; i < 4; ++i) {
        const float* r0 = xp + i * 1024;
        areg[i] = r0[0];   // a_i = x[n,c,i,xx,  yy  ]
        cq[i]   = r0[1];   // c_i = x[n,c,i,xx,  yy+1]
        bq[i]   = r0[32];  // b_i = x[n,c,i,xx+1,yy  ]
        dq[i]   = r0[33];  // d_i = x[n,c,i,xx+1,yy+1]
      }
      b0 = h ? bq[2] : bq[0];
      b1 = h ? bq[3] : bq[1];
#pragma unroll
      for (int k2 = 0; k2 < 4; ++k2)
#pragma unroll
        for (int l2 = 0; l2 < 4; ++l2)
          cdreg[k2 * 4 + l2] = cq[k2] * dq[l2];
    }
    barrier_lgkm();  // prev chunk's frag reads (lgkm) done before overwrite

    // ---- stage sW[po][m_local] from prefetched regs (12 floats = m pair x 6 o) ----
    {
      const float vv[12] = {wv0.x, wv0.y, wv0.z, wv0.w, wv1.x, wv1.y,
                            wv1.z, wv1.w, wv2.x, wv2.y, wv2.z, wv2.w};
#pragma unroll
      for (int o = 0; o < 6; ++o) {
        const unsigned pk = (unsigned)f2bf(vv[o]) | ((unsigned)f2bf(vv[o + 6]) << 16);
        *(unsigned*)&sW[(p_st * 6 + o) * SW_STR + 2 * q_st] = pk;
      }
    }
    // ---- stage sA[n][ij4*16+kl] = (a_mb * b_{2h+e}) * cd[kl] ----
#pragma unroll
    for (int e = 0; e < 2; ++e) {
      const float ab = areg[mb] * (e ? b1 : b0);
      unsigned pk[8];
#pragma unroll
      for (int u = 0; u < 8; ++u)
        pk[u] = (unsigned)f2bf(ab * cdreg[2 * u]) |
                ((unsigned)f2bf(ab * cdreg[2 * u + 1]) << 16);
      uintx4* dp = (uintx4*)&sA[n_st * SA_STR + (2 * h + e) * 16];
      uintx4 v0 = {pk[0], pk[1], pk[2], pk[3]};
      uintx4 v1 = {pk[4], pk[5], pk[6], pk[7]};
      dp[0] = v0;
      dp[1] = v1;
    }
    // ---- prefetch next chunk's W (rides across the barrier; consumed next
    //      chunk via register deps -> compiler inserts counted vmcnt wait) ----
    if (ch < 11) {
      const int cn = (ch + 1) >> 2, mbn = (ch + 1) & 3;
      const float* src = tensors +
          ((size_t)((cn * 8 + p_st) * 961 + site)) * 1536 + (mbn * 64 + 2 * q_st) * 6;
      wv0 = *(const float4*)src;
      wv1 = *(const float4*)(src + 4);
      wv2 = *(const float4*)(src + 8);
    }
    barrier_lgkm();  // ds_writes visible before frag reads; vmcnt NOT drained

    // ---- MFMA: 2 K-steps of 32, wave tile 2(M) x 3(N) ----
#pragma unroll
    for (int ks = 0; ks < 2; ++ks) {
      const int kof = ks * 32 + quad * 8;
      short8 af[2], bf[3];
#pragma unroll
      for (int mt = 0; mt < 2; ++mt)
        af[mt] = *(const short8*)&sA[(wave * 32 + mt * 16 + row) * SA_STR + kof];
#pragma unroll
      for (int nt = 0; nt < 3; ++nt)
        bf[nt] = *(const short8*)&sW[(nt * 16 + row) * SW_STR + kof];
#pragma unroll
      for (int mt = 0; mt < 2; ++mt)
#pragma unroll
        for (int nt = 0; nt < 3; ++nt)
          acc[mt][nt] = __builtin_amdgcn_mfma_f32_16x16x32_bf16(
              af[mt], bf[nt], acc[mt][nt], 0, 0, 0);
    }
  }

  // ---- epilogue: D row = quad*4+r (n-local), col = lane&15 (po-local) ----
  if (TO_WS) {
#pragma unroll
    for (int mt = 0; mt < 2; ++mt)
#pragma unroll
      for (int r = 0; r < 4; ++r) {
        const int n = wave * 32 + mt * 16 + quad * 4 + r;
#pragma unroll
        for (int nt = 0; nt < 3; ++nt) {
          const int po = nt * 16 + row;
          dst[(size_t)site * 6144 + n * 48 + po] = acc[mt][nt][r];
        }
      }
  } else {
#pragma unroll
    for (int mt = 0; mt < 2; ++mt)
#pragma unroll
      for (int r = 0; r < 4; ++r) {
        const int n = wave * 32 + mt * 16 + quad * 4 + r;
#pragma unroll
        for (int nt = 0; nt < 3; ++nt) {
          const int po = nt * 16 + row;
          const int p = po / 6, o = po - p * 6;
          dst[(size_t)(n * 48 + po) * 961 + site] =
              acc[mt][nt][r] + bias[(p * 961 + site) * 6 + o];
        }
      }
  }
}

// out[f*961 + site] = ws[site*6144 + f] + bias[(p*961+site)*6 + o],  f = n*48+p*6+o
__global__ __launch_bounds__(256, 8)
void ttn_transpose_bias(const float* __restrict__ ws,
                        const float* __restrict__ bias,
                        float* __restrict__ out) {
  __shared__ float tile[32][33];
  const int f0 = blockIdx.x * 32;
  const int s0 = blockIdx.y * 32;
  const int tx = threadIdx.x;       // 0..31
  const int ty = threadIdx.y;       // 0..7

#pragma unroll
  for (int rr = 0; rr < 4; ++rr) {
    const int srow = ty + rr * 8;
    const int site = s0 + srow;
    if (site < 961)
      tile[srow][tx] = ws[(size_t)site * 6144 + f0 + tx];
  }
  __syncthreads();

#pragma unroll
  for (int rr = 0; rr < 4; ++rr) {
    const int fy = ty + rr * 8;
    const int f = f0 + fy;
    const int site = s0 + tx;
    if (site < 961) {
      const int po = f % 48;
      const int p = po / 6, o = po - p * 6;
      out[(size_t)f * 961 + site] = tile[tx][fy] + bias[(p * 961 + site) * 6 + o];
    }
  }
}

extern "C" void kernel_launch(void* const* d_in, const int* in_sizes, int n_in,
                              void* d_out, int out_size, void* d_ws, size_t ws_size,
                              hipStream_t stream) {
  const float* x       = (const float*)d_in[0];
  const float* tensors = (const float*)d_in[1];
  const float* bias    = (const float*)d_in[2];
  float* out           = (float*)d_out;

  const size_t need = (size_t)WS_ELEMS * sizeof(float);
  if (d_ws != nullptr && ws_size >= need) {
    float* ws = (float*)d_ws;
    hipLaunchKernelGGL((ttn_conv_mfma<true>), dim3(961), dim3(256), 0, stream,
                       x, tensors, bias, ws);
    hipLaunchKernelGGL(ttn_transpose_bias, dim3(192, 31), dim3(32, 8), 0, stream,
                       ws, bias, out);
  } else {
    hipLaunchKernelGGL((ttn_conv_mfma<false>), dim3(961), dim3(256), 0, stream,
                       x, tensors, bias, out);
  }
}